// Round 4
// baseline (111.222 us; speedup 1.0000x reference)
//
#include <hip/hip_runtime.h>
#include <hip/hip_bf16.h>

// Problem constants (fixed by reference): N=4096, D=256, T=0.5, EPS=1e-8
#define PN   4096
#define PN2  8192
#define PD   256
#define TILE 256
#define BK   64
#define NBLK (PN2 / TILE)              // 32 tile-blocks per dim
#define NTRI (NBLK * (NBLK + 1) / 2)   // 528 upper-tri blocks (528 % 8 == 0)

typedef __attribute__((ext_vector_type(8))) short bf16x8;   // 8 bf16 = 4 VGPRs
typedef __attribute__((ext_vector_type(4))) float f32x4;

typedef const __attribute__((address_space(1))) void* gas_ptr;
typedef __attribute__((address_space(3))) void* las_ptr;

// ---------------------------------------------------------------------------
// Kernel 1: row-normalize z = [z_i; z_j] (fp32), write bf16 zn; zero the
// tiny finalize scratch. Wave-per-row: float4 loads, shuffle-reduce, 8B store.
// ---------------------------------------------------------------------------
__global__ __launch_bounds__(256) void normalize_kernel(
    const float* __restrict__ zi, const float* __restrict__ zj,
    __hip_bfloat16* __restrict__ zn, float* __restrict__ wlws,
    unsigned* __restrict__ ticket) {
  const int wave = threadIdx.x >> 6;
  const int lane = threadIdx.x & 63;
  const int r = blockIdx.x * 4 + wave;           // 0..8191
  const float* src = (r < PN) ? (zi + (size_t)r * PD) : (zj + (size_t)(r - PN) * PD);
  float4 x = *(const float4*)(src + lane * 4);   // 16B/lane, coalesced
  float s = x.x * x.x + x.y * x.y + x.z * x.z + x.w * x.w;
  #pragma unroll
  for (int off = 32; off >= 1; off >>= 1) s += __shfl_xor(s, off, 64);
  float inv = 1.0f / fmaxf(sqrtf(s), 1e-8f);
  union { ushort4 u; __hip_bfloat16 h[4]; } o;
  o.h[0] = __float2bfloat16(x.x * inv);
  o.h[1] = __float2bfloat16(x.y * inv);
  o.h[2] = __float2bfloat16(x.z * inv);
  o.h[3] = __float2bfloat16(x.w * inv);
  *(ushort4*)((unsigned short*)zn + (size_t)r * PD + lane * 4) = o.u;  // 8B/lane
  if (r == 0) {                                   // ws is poisoned 0xAA pre-launch
    if (lane == 0) { wlws[0] = 0.0f; wlws[1] = 0.0f; }
    if (lane == 1) *ticket = 0u;
  }
}

// ---------------------------------------------------------------------------
// Kernel 2: sim = zn @ zn^T, UPPER-TRIANGULAR 256x256 blocks (symmetry).
// 8 waves (512 thr), per-wave 128x64 output (acc[8][4] f32x4 = 128 VGPR).
// Single-barrier double-buffered staging (T3 minimum 2-phase): issue DMA for
// kt+1 BEFORE computing kt; one __syncthreads per step. 4x compute per staged
// byte vs the 128^2 version; total staged bytes halve (266 -> 131 MB).
// Epilogue: LDS accumulation, then unique-writer plain stores:
//   row-partials of (bi,bj) -> rowpart[bj][bi*256 ..), col -> rowpart[bi][bj*256 ..)
// XCD-aware bijective swizzle (528 % 8 == 0).
// ---------------------------------------------------------------------------
__global__ __launch_bounds__(512, 2) void simsum_kernel(
    const __hip_bfloat16* __restrict__ zn,
    float* __restrict__ rowpart, float* __restrict__ pos) {
  __shared__ char lds[2 * 2 * TILE * BK * 2];   // 128 KiB: [buf][As|Bs]
  __shared__ float rowacc[TILE];
  __shared__ float colacc[TILE];

  const int tid  = threadIdx.x;
  if (tid < TILE) { rowacc[tid] = 0.0f; colacc[tid] = 0.0f; }

  // XCD swizzle: 8 XCDs, 66 blocks each (bijective since 528 % 8 == 0)
  const int idx = (int)((blockIdx.x & 7) * (NTRI / 8) + (blockIdx.x >> 3));
  // Decode upper-tri (bi<=bj): idx = T(bj) + bi, T(bj)=bj(bj+1)/2
  int bj = (int)((sqrtf(8.0f * (float)idx + 1.0f) - 1.0f) * 0.5f);
  while ((bj + 1) * (bj + 2) / 2 <= idx) ++bj;
  while (bj * (bj + 1) / 2 > idx) --bj;
  const int bi = idx - bj * (bj + 1) / 2;
  const bool diagBlk = (bi == bj);
  const bool posBlk  = (bj == bi + PN / TILE);   // cols == rows + 4096

  const int wave = tid >> 6;           // 0..7
  const int lane = tid & 63;
  const int quad = lane >> 4;
  const int c16  = lane & 15;
  const int rowBase = bi * TILE;
  const int colBase = bj * TILE;
  const int waveRow = (wave >> 2) * 128;   // 0,128
  const int waveCol = (wave & 3) * 64;     // 0,64,128,192
  const int subrow = lane >> 3;  // 0..7 (row within an 8-row issue)
  const int slot   = lane & 7;   // 0..7 (16B chunk slot within a 128B LDS row)

  f32x4 acc[8][4];
  #pragma unroll
  for (int i = 0; i < 8; ++i)
    #pragma unroll
    for (int j = 0; j < 4; ++j)
      acc[i][j] = (f32x4){0.f, 0.f, 0.f, 0.f};

  // Stage one BK=64 K-slab of A (and B if off-diag): 32 issues x 1 KiB each
  // (8 rows x 128B), pre-swizzled global source, linear LDS dest (rule #21).
#define STAGE(DSTA, DSTB, KT) do {                                            \
    _Pragma("unroll")                                                         \
    for (int p = 0; p < 4; ++p) {                                             \
      int issue = wave * 4 + p;            /* 0..31, wave-uniform */          \
      int rr = issue * 8 + subrow;         /* tile row 0..255 */              \
      int cc = slot ^ (rr & 7);            /* swizzled k-chunk */             \
      const __hip_bfloat16* ga = zn + (size_t)(rowBase + rr) * PD + (KT) * BK + cc * 8; \
      __builtin_amdgcn_global_load_lds((gas_ptr)ga, (las_ptr)((DSTA) + issue * 1024), 16, 0, 0); \
      if (!diagBlk) {                                                         \
        const __hip_bfloat16* gb = zn + (size_t)(colBase + rr) * PD + (KT) * BK + cc * 8; \
        __builtin_amdgcn_global_load_lds((gas_ptr)gb, (las_ptr)((DSTB) + issue * 1024), 16, 0, 0); \
      }                                                                       \
    }                                                                         \
  } while (0)

  STAGE(lds, lds + 32768, 0);
  __syncthreads();

  for (int kt = 0; kt < PD / BK; ++kt) {         // 4 kt steps
    char* As = lds + (kt & 1) * 65536;
    char* Bs = As + 32768;
    if (kt < PD / BK - 1) {                      // prefetch next slab (dbuf)
      char* An = lds + ((kt + 1) & 1) * 65536;
      STAGE(An, An + 32768, kt + 1);
    }
    const char* BsEff = diagBlk ? As : Bs;

    #pragma unroll
    for (int ki = 0; ki < 2; ++ki) {             // two k=32 MFMA steps per BK=64
      bf16x8 b[4];
      #pragma unroll
      for (int ni = 0; ni < 4; ++ni) {
        int r = waveCol + ni * 16 + c16;         // B "row" of zn = sim column n
        int ch = quad + ki * 4;
        b[ni] = *(const bf16x8*)(BsEff + r * 128 + ((ch ^ (r & 7)) * 16));
      }
      #pragma unroll
      for (int mi = 0; mi < 8; ++mi) {
        int r = waveRow + mi * 16 + c16;         // A row: m = lane&15
        int ch = quad + ki * 4;
        bf16x8 a = *(const bf16x8*)(As + r * 128 + ((ch ^ (r & 7)) * 16));
        #pragma unroll
        for (int ni = 0; ni < 4; ++ni)
          acc[mi][ni] = __builtin_amdgcn_mfma_f32_16x16x32_bf16(a, b[ni], acc[mi][ni], 0, 0, 0);
      }
    }
    if (kt < PD / BK - 1) __syncthreads();       // one barrier per step
  }
#undef STAGE

  // Epilogue. C/D layout: col=lane&15, row=quad*4+reg  [measured m89/m91]
  float colsum[4] = {0.f, 0.f, 0.f, 0.f};   // per-ni column partials (off-diag)
  #pragma unroll
  for (int mi = 0; mi < 8; ++mi) {
    int lrow = waveRow + mi * 16 + quad * 4;      // local row 0..255
    float rs[4] = {0.f, 0.f, 0.f, 0.f};
    #pragma unroll
    for (int ni = 0; ni < 4; ++ni) {
      int gcol = colBase + waveCol + ni * 16 + c16;
      #pragma unroll
      for (int t = 0; t < 4; ++t) {
        int grow = rowBase + lrow + t;
        float sim = acc[mi][ni][t];
        float e = __expf(2.0f * sim);               // exp(sim / T), T=0.5
        if (diagBlk && gcol == grow) e = 0.0f;      // mask diagonal
        rs[t] += e;
        colsum[ni] += e;
        if (posBlk && gcol == grow + PN) {          // positive pair (and mirror)
          pos[grow] = sim;                           // unique writer per row
          pos[grow + PN] = sim;
        }
      }
    }
    #pragma unroll
    for (int t = 0; t < 4; ++t) {
      #pragma unroll
      for (int off = 1; off <= 8; off <<= 1) rs[t] += __shfl_xor(rs[t], off, 64);
    }
    if (c16 == 0) {                                  // LDS atomics: cheap, per-CU
      #pragma unroll
      for (int t = 0; t < 4; ++t) atomicAdd(&rowacc[lrow + t], rs[t]);
    }
  }
  if (!diagBlk) {   // column contributions = mirrored rows (symmetry)
    #pragma unroll
    for (int ni = 0; ni < 4; ++ni) {
      float cs = colsum[ni];
      cs += __shfl_xor(cs, 16, 64);
      cs += __shfl_xor(cs, 32, 64);
      if (quad == 0) atomicAdd(&colacc[waveCol + ni * 16 + c16], cs);
    }
  }

  __syncthreads();                // all LDS accumulation done
  if (tid < TILE) {               // plain stores, unique writers (see header)
    rowpart[(size_t)bj * PN2 + rowBase + tid] = rowacc[tid];
    if (!diagBlk)
      rowpart[(size_t)bi * PN2 + colBase + tid] = colacc[tid];
  }
}

// ---------------------------------------------------------------------------
// Kernel 3: rowsum[r] = sum_x rowpart[x][r]; loss_r = log(rowsum)-2*pos;
// out = sum(w*loss)/sum(w). 32 blocks x 256 threads, 1 row/thread.
// ---------------------------------------------------------------------------
__global__ __launch_bounds__(256) void finalize_kernel(
    const float* __restrict__ rowpart, const float* __restrict__ pos,
    const float* __restrict__ w, float* __restrict__ wlws,
    unsigned* __restrict__ ticket, float* __restrict__ out) {
  const int tid = threadIdx.x;
  const int r = blockIdx.x * 256 + tid;     // 32*256 = 8192
  float s = 0.0f;
  #pragma unroll
  for (int x = 0; x < NBLK; ++x) s += rowpart[(size_t)x * PN2 + r];
  float li = logf(s) - 2.0f * pos[r];
  float wi = w[r & (PN - 1)];
  float wl = wi * li, ws = wi;
  #pragma unroll
  for (int off = 32; off >= 1; off >>= 1) {
    wl += __shfl_xor(wl, off, 64);
    ws += __shfl_xor(ws, off, 64);
  }
  __shared__ float pl[4], pw[4];
  const int lane = tid & 63, wv = tid >> 6;
  if (lane == 0) { pl[wv] = wl; pw[wv] = ws; }
  __syncthreads();
  if (tid == 0) {
    atomicAdd(&wlws[0], pl[0] + pl[1] + pl[2] + pl[3]);
    atomicAdd(&wlws[1], pw[0] + pw[1] + pw[2] + pw[3]);
    __threadfence();
    if (atomicAdd(ticket, 1u) == 31) {      // last of 32 blocks
      float a = atomicAdd(&wlws[0], 0.0f);  // coherent re-read
      float b = atomicAdd(&wlws[1], 0.0f);
      out[0] = a / b;
    }
  }
}

// ---------------------------------------------------------------------------
extern "C" void kernel_launch(void* const* d_in, const int* in_sizes, int n_in,
                              void* d_out, int out_size, void* d_ws, size_t ws_size,
                              hipStream_t stream) {
  const float* zi = (const float*)d_in[0];
  const float* zj = (const float*)d_in[1];
  const float* w  = (const float*)d_in[2];
  float* out = (float*)d_out;

  // Workspace: zn bf16[8192*256]=4MiB | rowpart f32[32][8192]=1MiB |
  //            pos f32[8192]=32KiB | wlws f32[2] | ticket u32
  __hip_bfloat16* zn = (__hip_bfloat16*)d_ws;
  float* rowpart = (float*)((char*)d_ws + (size_t)PN2 * PD * 2);
  float* pos     = rowpart + (size_t)NBLK * PN2;
  float* wlws    = pos + PN2;
  unsigned* ticket = (unsigned*)(wlws + 2);

  normalize_kernel<<<PN2 / 4, 256, 0, stream>>>(zi, zj, zn, wlws, ticket);
  simsum_kernel<<<NTRI, 512, 0, stream>>>(zn, rowpart, pos);
  finalize_kernel<<<32, 256, 0, stream>>>(rowpart, pos, w, wlws, ticket, out);
}